// Round 2
// baseline (322.977 us; speedup 1.0000x reference)
//
#include <hip/hip_runtime.h>
#include <math.h>

#define INC 64
#define HID 16
#define NB 8

__device__ __forceinline__ void atomicMaxF(float* addr, float val) {
    // standard float-max-via-int trick: valid for mixed signs, init to -inf
    if (val >= 0.0f) atomicMax((int*)addr, __float_as_int(val));
    else             atomicMin((unsigned int*)addr, __float_as_uint(val));
}

// ---------------- init workspace (ws is poisoned 0xAA before every launch) ---
__global__ void k_init(float* seg_sum, float* seg_max, int* counts, float* sm_pad) {
    int t = threadIdx.x;
    if (t < NB * INC) { seg_sum[t] = 0.0f; seg_max[t] = -INFINITY; }
    else if (t < NB * INC + NB) counts[t - NB * INC] = 0;
    else if (t < NB * INC + NB + 2) sm_pad[t - NB * INC - NB] = 0.0f; // pad row N
}

// ------------- segmented sum/max/count over sorted batch_idx -----------------
// wave = 64 lanes; lane L handles channels (L&15)*4 .. +3 of point p + (L>>4).
// Each wave owns a contiguous chunk; batch transitions are rare (8 total),
// so register-accumulate, flush via atomics on transition.
__global__ void k_reduce(const float* __restrict__ F, const int* __restrict__ bidx,
                         float* __restrict__ seg_sum, float* __restrict__ seg_max,
                         int* __restrict__ counts, int N, int CHUNK) {
    int lane = threadIdx.x & 63;
    int wave = (blockIdx.x * blockDim.x + threadIdx.x) >> 6;
    int start = wave * CHUNK;
    if (start >= N) return;
    int pend = min(start + CHUNK, N);
    int sub = lane >> 4;
    int ch  = (lane & 15) << 2;
    bool isCnt = (lane & 15) == 0;

    float4 sum = make_float4(0.f, 0.f, 0.f, 0.f);
    float4 mx  = make_float4(-INFINITY, -INFINITY, -INFINITY, -INFINITY);
    int cnt = 0, cur = -1;

    for (int p = start; p < pend; p += 4) {
        int pp = p + sub;
        int b = (pp < pend) ? bidx[pp] : -2;
        if (b != cur) {
            if (cur >= 0) {
                float* ss = seg_sum + cur * INC + ch;
                atomicAdd(ss + 0, sum.x); atomicAdd(ss + 1, sum.y);
                atomicAdd(ss + 2, sum.z); atomicAdd(ss + 3, sum.w);
                float* sx = seg_max + cur * INC + ch;
                atomicMaxF(sx + 0, mx.x); atomicMaxF(sx + 1, mx.y);
                atomicMaxF(sx + 2, mx.z); atomicMaxF(sx + 3, mx.w);
                if (isCnt && cnt) atomicAdd(&counts[cur], cnt);
            }
            sum = make_float4(0.f, 0.f, 0.f, 0.f);
            mx  = make_float4(-INFINITY, -INFINITY, -INFINITY, -INFINITY);
            cnt = 0; cur = b;
        }
        if (b >= 0) {
            const float4 v = *reinterpret_cast<const float4*>(F + pp * INC + ch);
            sum.x += v.x; sum.y += v.y; sum.z += v.z; sum.w += v.w;
            mx.x = fmaxf(mx.x, v.x); mx.y = fmaxf(mx.y, v.y);
            mx.z = fmaxf(mx.z, v.z); mx.w = fmaxf(mx.w, v.w);
            cnt += (int)isCnt;
        }
    }
    if (cur >= 0) {
        float* ss = seg_sum + cur * INC + ch;
        atomicAdd(ss + 0, sum.x); atomicAdd(ss + 1, sum.y);
        atomicAdd(ss + 2, sum.z); atomicAdd(ss + 3, sum.w);
        float* sx = seg_max + cur * INC + ch;
        atomicMaxF(sx + 0, mx.x); atomicMaxF(sx + 1, mx.y);
        atomicMaxF(sx + 2, mx.z); atomicMaxF(sx + 3, mx.w);
        if (isCnt && cnt) atomicAdd(&counts[cur], cnt);
    }
}

// -------- tiny per-batch MLP: gate[b][c] = sigmoid(mlp(avg)+mlp(mx)) ---------
__global__ void k_gate(const float* __restrict__ seg_sum, const float* __restrict__ seg_max,
                       const int* __restrict__ counts,
                       const float* __restrict__ W1, const float* __restrict__ b1,
                       const float* __restrict__ W2, const float* __restrict__ b2,
                       float* __restrict__ gate) {
    __shared__ float s_avg[NB * INC], s_mx[NB * INC];
    __shared__ float s_ha[NB * HID], s_hm[NB * HID];
    int t = threadIdx.x; // 512 threads
    {
        int b = t >> 6;
        float c = (float)counts[b];
        s_avg[t] = seg_sum[t] / c;
        s_mx[t]  = seg_max[t];
    }
    __syncthreads();
    if (t < NB * HID) {
        int b = t >> 4, j = t & (HID - 1);
        float ha = b1[j], hm = b1[j];
        for (int c = 0; c < INC; ++c) {
            float w = W1[c * HID + j];
            ha += s_avg[b * INC + c] * w;
            hm += s_mx[b * INC + c] * w;
        }
        s_ha[t] = fmaxf(ha, 0.f);
        s_hm[t] = fmaxf(hm, 0.f);
    }
    __syncthreads();
    {
        int b = t >> 6, c = t & 63;
        float o = 2.f * b2[c];
        for (int j = 0; j < HID; ++j)
            o += (s_ha[b * HID + j] + s_hm[b * HID + j]) * W2[j * INC + c];
        gate[t] = 1.f / (1.f + expf(-o));
    }
}

// ------- per-point channel mean/max of z = F*gate -> sm[N][2] ---------------
__global__ void k_sm(const float* __restrict__ F, const int* __restrict__ bidx,
                     const float* __restrict__ gate, float* __restrict__ sm, int N) {
    int lane = threadIdx.x & 63;
    int wave = (blockIdx.x * blockDim.x + threadIdx.x) >> 6;
    int nwaves = (gridDim.x * blockDim.x) >> 6;
    int sub = lane >> 4, ch = (lane & 15) << 2;
    for (int p0 = wave * 4; p0 < N; p0 += nwaves * 4) {
        int pp = p0 + sub;
        float s = 0.f, m = -INFINITY;
        if (pp < N) {
            int b = bidx[pp];
            float4 v = *reinterpret_cast<const float4*>(F + pp * INC + ch);
            float4 g = *reinterpret_cast<const float4*>(gate + b * INC + ch);
            float4 z = make_float4(v.x * g.x, v.y * g.y, v.z * g.z, v.w * g.w);
            s = z.x + z.y + z.z + z.w;
            m = fmaxf(fmaxf(z.x, z.y), fmaxf(z.z, z.w));
        }
        // reduce across the 16 lanes of this point's group (xor masks 1..8)
        for (int msk = 1; msk < 16; msk <<= 1) {
            s += __shfl_xor(s, msk);
            m = fmaxf(m, __shfl_xor(m, msk));
        }
        if ((lane & 15) == 0 && pp < N) {
            *reinterpret_cast<float2*>(sm + pp * 2) = make_float2(s * (1.f / 64.f), m);
        }
    }
}

// ------- gather 27 neighbors' sm, 2ch conv, final out = z * sigmoid(c) ------
__global__ void k_out(const float* __restrict__ F, const int* __restrict__ bidx,
                      const int* __restrict__ nbr, const float* __restrict__ gate,
                      const float* __restrict__ sm, const float* __restrict__ cw,
                      float* __restrict__ out, int N) {
    int lane = threadIdx.x & 63;
    int j = lane & 15;
    int sub = lane >> 4, ch = (lane & 15) << 2;
    // per-lane conv weights: k = j and k = 16+j (j<11); [k][0]=mean, [k][1]=max
    float2 cwa = make_float2(cw[2 * j], cw[2 * j + 1]);
    float2 cwb = (j < 11) ? make_float2(cw[2 * (16 + j)], cw[2 * (16 + j) + 1])
                          : make_float2(0.f, 0.f);
    int wave = (blockIdx.x * blockDim.x + threadIdx.x) >> 6;
    int nwaves = (gridDim.x * blockDim.x) >> 6;
    for (int p0 = wave * 4; p0 < N; p0 += nwaves * 4) {
        int pp = p0 + sub;
        float cpart = 0.f;
        if (pp < N) {
            int rb = pp * 27;
            int i1 = nbr[rb + j];
            int i2 = (j < 11) ? nbr[rb + 16 + j] : N;   // row N = zero pad
            float2 a = *reinterpret_cast<const float2*>(sm + i1 * 2);
            float2 b = *reinterpret_cast<const float2*>(sm + i2 * 2);
            cpart = a.x * cwa.x + a.y * cwa.y + b.x * cwb.x + b.y * cwb.y;
        }
        for (int msk = 1; msk < 16; msk <<= 1) cpart += __shfl_xor(cpart, msk);
        if (pp < N) {
            float sig = 1.f / (1.f + expf(-cpart));
            int b = bidx[pp];
            float4 v = *reinterpret_cast<const float4*>(F + pp * INC + ch);
            float4 g = *reinterpret_cast<const float4*>(gate + b * INC + ch);
            float4 o = make_float4(v.x * g.x * sig, v.y * g.y * sig,
                                   v.z * g.z * sig, v.w * g.w * sig);
            *reinterpret_cast<float4*>(out + pp * INC + ch) = o;
        }
    }
}

extern "C" void kernel_launch(void* const* d_in, const int* in_sizes, int n_in,
                              void* d_out, int out_size, void* d_ws, size_t ws_size,
                              hipStream_t stream) {
    const float* F    = (const float*)d_in[0];
    const int*   bidx = (const int*)d_in[1];
    const int*   nbr  = (const int*)d_in[2];
    const float* W1   = (const float*)d_in[3];
    const float* b1   = (const float*)d_in[4];
    const float* W2   = (const float*)d_in[5];
    const float* b2   = (const float*)d_in[6];
    const float* cw   = (const float*)d_in[7];
    float* out = (float*)d_out;
    int N = in_sizes[1];

    float* ws      = (float*)d_ws;
    float* seg_sum = ws;                 // 512
    float* seg_max = ws + NB * INC;      // 512
    int*   counts  = (int*)(ws + 2 * NB * INC); // 8
    float* gate    = ws + 2 * NB * INC + 16;    // 512
    float* sm      = ws + 3 * NB * INC + 32;    // (N+1)*2, 8B-aligned

    k_init<<<1, 1024, 0, stream>>>(seg_sum, seg_max, counts, sm + (size_t)N * 2);

    const int waves = 1024;              // 256 blocks x 256 threads
    int chunk = ((N + waves * 4 - 1) / (waves * 4)) * 4;
    k_reduce<<<256, 256, 0, stream>>>(F, bidx, seg_sum, seg_max, counts, N, chunk);

    k_gate<<<1, 512, 0, stream>>>(seg_sum, seg_max, counts, W1, b1, W2, b2, gate);

    k_sm<<<1024, 256, 0, stream>>>(F, bidx, gate, sm, N);

    k_out<<<1024, 256, 0, stream>>>(F, bidx, nbr, gate, sm, cw, out, N);
}

// Round 3
// 249.317 us; speedup vs baseline: 1.2954x; 1.2954x over previous
//
#include <hip/hip_runtime.h>
#include <math.h>

#define INC 64
#define HID 16
#define NB 8

__device__ __forceinline__ void atomicMaxF(float* addr, float val) {
    // float-max-via-int trick: valid for mixed signs, target initialized to -inf
    if (val >= 0.0f) atomicMax((int*)addr, __float_as_int(val));
    else             atomicMin((unsigned int*)addr, __float_as_uint(val));
}

// ---------------- init workspace (ws is poisoned 0xAA before every launch) ---
__global__ void k_init(float* seg_sum, float* seg_max, int* counts, float* sm_pad) {
    int t = threadIdx.x;
    if (t < NB * INC) { seg_sum[t] = 0.0f; seg_max[t] = -INFINITY; }
    else if (t < NB * INC + NB) counts[t - NB * INC] = 0;
    else if (t < NB * INC + NB + 2) sm_pad[t - NB * INC - NB] = 0.0f; // pad row N
}

// ------------- segmented sum/max/count over sorted batch_idx -----------------
// wave = 64 lanes; lane L: sub = L>>4 (which of 4 points), ch = (L&15)*4.
// batch_idx is sorted with only B-1=7 transitions, so a wave checks ONCE
// whether its chunk is batch-uniform; fast path streams F with no bidx loads.
__global__ void k_reduce(const float* __restrict__ F, const int* __restrict__ bidx,
                         float* __restrict__ seg_sum, float* __restrict__ seg_max,
                         int* __restrict__ counts, int N, int CHUNK) {
    int lane = threadIdx.x & 63;
    int wave = (blockIdx.x * blockDim.x + threadIdx.x) >> 6;
    int start = wave * CHUNK;
    if (start >= N) return;
    int pend = min(start + CHUNK, N);   // pend-start is a multiple of 4 (N%4==0)
    int sub = lane >> 4;
    int ch  = (lane & 15) << 2;

    int bfirst = bidx[start];
    int blast  = bidx[pend - 1];

    if (bfirst == blast) {
        // ---- fast path: uniform batch, pure float4 streaming ----
        float4 sum = make_float4(0.f, 0.f, 0.f, 0.f);
        float4 mx  = make_float4(-INFINITY, -INFINITY, -INFINITY, -INFINITY);
        #pragma unroll 4
        for (int p = start; p < pend; p += 4) {
            const float4 v = *reinterpret_cast<const float4*>(F + (size_t)(p + sub) * INC + ch);
            sum.x += v.x; sum.y += v.y; sum.z += v.z; sum.w += v.w;
            mx.x = fmaxf(mx.x, v.x); mx.y = fmaxf(mx.y, v.y);
            mx.z = fmaxf(mx.z, v.z); mx.w = fmaxf(mx.w, v.w);
        }
        // combine the 4 sub-copies (lanes differing in bits 4,5) before atomics
        #pragma unroll
        for (int msk = 16; msk < 64; msk <<= 1) {
            sum.x += __shfl_xor(sum.x, msk); sum.y += __shfl_xor(sum.y, msk);
            sum.z += __shfl_xor(sum.z, msk); sum.w += __shfl_xor(sum.w, msk);
            mx.x = fmaxf(mx.x, __shfl_xor(mx.x, msk));
            mx.y = fmaxf(mx.y, __shfl_xor(mx.y, msk));
            mx.z = fmaxf(mx.z, __shfl_xor(mx.z, msk));
            mx.w = fmaxf(mx.w, __shfl_xor(mx.w, msk));
        }
        if (sub == 0) {
            float* ss = seg_sum + bfirst * INC + ch;
            atomicAdd(ss + 0, sum.x); atomicAdd(ss + 1, sum.y);
            atomicAdd(ss + 2, sum.z); atomicAdd(ss + 3, sum.w);
            float* sx = seg_max + bfirst * INC + ch;
            atomicMaxF(sx + 0, mx.x); atomicMaxF(sx + 1, mx.y);
            atomicMaxF(sx + 2, mx.z); atomicMaxF(sx + 3, mx.w);
            if (lane == 0) atomicAdd(&counts[bfirst], pend - start);
        }
        return;
    }

    // ---- slow path (<= B-1 = 7 waves total): per-point batch tracking ----
    bool isCnt = (lane & 15) == 0;
    float4 sum = make_float4(0.f, 0.f, 0.f, 0.f);
    float4 mx  = make_float4(-INFINITY, -INFINITY, -INFINITY, -INFINITY);
    int cnt = 0, cur = -1;
    for (int p = start; p < pend; p += 4) {
        int pp = p + sub;
        int b = bidx[pp];
        if (b != cur) {
            if (cur >= 0) {
                float* ss = seg_sum + cur * INC + ch;
                atomicAdd(ss + 0, sum.x); atomicAdd(ss + 1, sum.y);
                atomicAdd(ss + 2, sum.z); atomicAdd(ss + 3, sum.w);
                float* sx = seg_max + cur * INC + ch;
                atomicMaxF(sx + 0, mx.x); atomicMaxF(sx + 1, mx.y);
                atomicMaxF(sx + 2, mx.z); atomicMaxF(sx + 3, mx.w);
                if (isCnt && cnt) atomicAdd(&counts[cur], cnt);
            }
            sum = make_float4(0.f, 0.f, 0.f, 0.f);
            mx  = make_float4(-INFINITY, -INFINITY, -INFINITY, -INFINITY);
            cnt = 0; cur = b;
        }
        const float4 v = *reinterpret_cast<const float4*>(F + (size_t)pp * INC + ch);
        sum.x += v.x; sum.y += v.y; sum.z += v.z; sum.w += v.w;
        mx.x = fmaxf(mx.x, v.x); mx.y = fmaxf(mx.y, v.y);
        mx.z = fmaxf(mx.z, v.z); mx.w = fmaxf(mx.w, v.w);
        cnt += (int)isCnt;
    }
    if (cur >= 0) {
        float* ss = seg_sum + cur * INC + ch;
        atomicAdd(ss + 0, sum.x); atomicAdd(ss + 1, sum.y);
        atomicAdd(ss + 2, sum.z); atomicAdd(ss + 3, sum.w);
        float* sx = seg_max + cur * INC + ch;
        atomicMaxF(sx + 0, mx.x); atomicMaxF(sx + 1, mx.y);
        atomicMaxF(sx + 2, mx.z); atomicMaxF(sx + 3, mx.w);
        if (isCnt && cnt) atomicAdd(&counts[cur], cnt);
    }
}

// -------- tiny per-batch MLP: gate[b][c] = sigmoid(mlp(avg)+mlp(mx)) ---------
__global__ void k_gate(const float* __restrict__ seg_sum, const float* __restrict__ seg_max,
                       const int* __restrict__ counts,
                       const float* __restrict__ W1, const float* __restrict__ b1,
                       const float* __restrict__ W2, const float* __restrict__ b2,
                       float* __restrict__ gate) {
    __shared__ float s_avg[NB * INC], s_mx[NB * INC];
    __shared__ float s_ha[NB * HID], s_hm[NB * HID];
    int t = threadIdx.x; // 512 threads
    {
        int b = t >> 6;
        float c = (float)counts[b];
        s_avg[t] = seg_sum[t] / c;
        s_mx[t]  = seg_max[t];
    }
    __syncthreads();
    if (t < NB * HID) {
        int b = t >> 4, j = t & (HID - 1);
        float ha = b1[j], hm = b1[j];
        for (int c = 0; c < INC; ++c) {
            float w = W1[c * HID + j];
            ha += s_avg[b * INC + c] * w;
            hm += s_mx[b * INC + c] * w;
        }
        s_ha[t] = fmaxf(ha, 0.f);
        s_hm[t] = fmaxf(hm, 0.f);
    }
    __syncthreads();
    {
        int b = t >> 6, c = t & 63;
        float o = 2.f * b2[c];
        for (int j = 0; j < HID; ++j)
            o += (s_ha[b * HID + j] + s_hm[b * HID + j]) * W2[j * INC + c];
        gate[t] = 1.f / (1.f + expf(-o));
    }
}

// ------- per-point channel mean/max of z = F*gate -> sm[N][2] ---------------
__global__ void k_sm(const float* __restrict__ F, const int* __restrict__ bidx,
                     const float* __restrict__ gate, float* __restrict__ sm, int N) {
    int lane = threadIdx.x & 63;
    int wave = (blockIdx.x * blockDim.x + threadIdx.x) >> 6;
    int nwaves = (gridDim.x * blockDim.x) >> 6;
    int sub = lane >> 4, ch = (lane & 15) << 2;
    for (int p0 = wave * 4; p0 < N; p0 += nwaves * 4) {
        int pp = p0 + sub;
        float s = 0.f, m = -INFINITY;
        if (pp < N) {
            int b = bidx[pp];
            float4 v = *reinterpret_cast<const float4*>(F + (size_t)pp * INC + ch);
            float4 g = *reinterpret_cast<const float4*>(gate + b * INC + ch);
            float4 z = make_float4(v.x * g.x, v.y * g.y, v.z * g.z, v.w * g.w);
            s = z.x + z.y + z.z + z.w;
            m = fmaxf(fmaxf(z.x, z.y), fmaxf(z.z, z.w));
        }
        #pragma unroll
        for (int msk = 1; msk < 16; msk <<= 1) {
            s += __shfl_xor(s, msk);
            m = fmaxf(m, __shfl_xor(m, msk));
        }
        if ((lane & 15) == 0 && pp < N) {
            *reinterpret_cast<float2*>(sm + (size_t)pp * 2) = make_float2(s * (1.f / 64.f), m);
        }
    }
}

// ------- gather 27 neighbors' sm, 2ch conv, final out = z * sigmoid(c) ------
__global__ void k_out(const float* __restrict__ F, const int* __restrict__ bidx,
                      const int* __restrict__ nbr, const float* __restrict__ gate,
                      const float* __restrict__ sm, const float* __restrict__ cw,
                      float* __restrict__ out, int N) {
    int lane = threadIdx.x & 63;
    int j = lane & 15;
    int sub = lane >> 4, ch = (lane & 15) << 2;
    // per-lane conv weights: k = j and k = 16+j (j<11); [k][0]=mean, [k][1]=max
    float2 cwa = make_float2(cw[2 * j], cw[2 * j + 1]);
    float2 cwb = (j < 11) ? make_float2(cw[2 * (16 + j)], cw[2 * (16 + j) + 1])
                          : make_float2(0.f, 0.f);
    int wave = (blockIdx.x * blockDim.x + threadIdx.x) >> 6;
    int nwaves = (gridDim.x * blockDim.x) >> 6;
    for (int p0 = wave * 4; p0 < N; p0 += nwaves * 4) {
        int pp = p0 + sub;
        float cpart = 0.f;
        if (pp < N) {
            int rb = pp * 27;
            int i1 = nbr[rb + j];
            int i2 = (j < 11) ? nbr[rb + 16 + j] : N;   // row N = zero pad
            float2 a = *reinterpret_cast<const float2*>(sm + (size_t)i1 * 2);
            float2 b = *reinterpret_cast<const float2*>(sm + (size_t)i2 * 2);
            cpart = a.x * cwa.x + a.y * cwa.y + b.x * cwb.x + b.y * cwb.y;
        }
        #pragma unroll
        for (int msk = 1; msk < 16; msk <<= 1) cpart += __shfl_xor(cpart, msk);
        if (pp < N) {
            float sig = 1.f / (1.f + expf(-cpart));
            int b = bidx[pp];
            float4 v = *reinterpret_cast<const float4*>(F + (size_t)pp * INC + ch);
            float4 g = *reinterpret_cast<const float4*>(gate + b * INC + ch);
            float4 o = make_float4(v.x * g.x * sig, v.y * g.y * sig,
                                   v.z * g.z * sig, v.w * g.w * sig);
            *reinterpret_cast<float4*>(out + (size_t)pp * INC + ch) = o;
        }
    }
}

extern "C" void kernel_launch(void* const* d_in, const int* in_sizes, int n_in,
                              void* d_out, int out_size, void* d_ws, size_t ws_size,
                              hipStream_t stream) {
    const float* F    = (const float*)d_in[0];
    const int*   bidx = (const int*)d_in[1];
    const int*   nbr  = (const int*)d_in[2];
    const float* W1   = (const float*)d_in[3];
    const float* b1   = (const float*)d_in[4];
    const float* W2   = (const float*)d_in[5];
    const float* b2   = (const float*)d_in[6];
    const float* cw   = (const float*)d_in[7];
    float* out = (float*)d_out;
    int N = in_sizes[1];

    float* ws      = (float*)d_ws;
    float* seg_sum = ws;                 // 512
    float* seg_max = ws + NB * INC;      // 512
    int*   counts  = (int*)(ws + 2 * NB * INC); // 8
    float* gate    = ws + 2 * NB * INC + 16;    // 512
    float* sm      = ws + 3 * NB * INC + 32;    // (N+1)*2, 8B-aligned

    k_init<<<1, 1024, 0, stream>>>(seg_sum, seg_max, counts, sm + (size_t)N * 2);

    // 512 blocks x 256 thr = 2048 waves (2/SIMD); each wave owns a contiguous chunk
    const int waves = 2048;
    int chunk = ((N + waves * 4 - 1) / (waves * 4)) * 4;
    k_reduce<<<512, 256, 0, stream>>>(F, bidx, seg_sum, seg_max, counts, N, chunk);

    k_gate<<<1, 512, 0, stream>>>(seg_sum, seg_max, counts, W1, b1, W2, b2, gate);

    k_sm<<<2048, 256, 0, stream>>>(F, bidx, gate, sm, N);

    k_out<<<2048, 256, 0, stream>>>(F, bidx, nbr, gate, sm, cw, out, N);
}